// Round 11
// baseline (107.840 us; speedup 1.0000x reference)
//
#include <hip/hip_runtime.h>

#define IN_FEATURES 512
#define NBLOCKS  2048
#define NTHREADS 256
#define JUNROLL  8        // 8 x 256 chunks = 32 KB contiguous per block per iter

typedef float f32x4 __attribute__((ext_vector_type(4)));

// R10 confirmed: dense moving window + long per-block contiguous bursts is
// the winning structure (137 -> 103 us). This round: single knob, burst
// length 16 KB -> 32 KB (JUNROLL 4 -> 8).
__global__ __launch_bounds__(256) void bspline_basis_kernel(
    const float* __restrict__ x,
    const float* __restrict__ grid,
    f32x4* __restrict__ out4,
    int total_chunks)
{
    int t = threadIdx.x;
    int b = blockIdx.x;

    float g3    = grid[3];        // first in-range knot (= -0.5)
    float h     = grid[4] - g3;   // uniform spacing (= 0.4)
    float inv_h = 1.0f / h;

    int m0 = (t & 1) << 2;        // half of the 8-wide row (invariant)

    const int per_iter = NBLOCKS * NTHREADS * JUNROLL;   // 4,194,304 chunks

    for (int base = b * (NTHREADS * JUNROLL) + t; base < total_chunks; base += per_iter) {
        // ---- issue all 8 x-loads first (memory-level parallelism) ----
        float xv[JUNROLL];
        #pragma unroll
        for (int j = 0; j < JUNROLL; ++j) {
            int c = base + j * NTHREADS;
            xv[j] = x[c >> 1];
        }

        // ---- compute 8 chunks ----
        f32x4 r[JUNROLL];
        #pragma unroll
        for (int j = 0; j < JUNROLL; ++j) {
            float u  = (xv[j] - g3) * inv_h;
            float fj = floorf(u);
            int jo = (int)fj;
            jo = jo < 0 ? 0 : (jo > 4 ? 4 : jo);
            float tt = u - (float)jo;

            float omt  = 1.0f - tt;
            float t2   = tt * tt;
            float t3   = t2 * tt;
            float omt3 = omt * omt * omt;
            const float k6 = 1.0f / 6.0f;
            float b0 = omt3 * k6;
            float b1 = (3.0f * t3 - 6.0f * t2 + 4.0f) * k6;
            float b2 = (-3.0f * t3 + 3.0f * t2 + 3.0f * tt + 1.0f) * k6;
            float b3 = t3 * k6;

            f32x4 rr;
            #pragma unroll
            for (int q = 0; q < 4; ++q) {
                int s = (m0 + q) - jo;
                float val = 0.0f;
                val = (s == 0) ? b0 : val;
                val = (s == 1) ? b1 : val;
                val = (s == 2) ? b2 : val;
                val = (s == 3) ? b3 : val;
                rr[q] = val;
            }
            r[j] = rr;
        }

        // ---- 8 back-to-back stores: block covers 32 KB contiguous ----
        #pragma unroll
        for (int j = 0; j < JUNROLL; ++j) {
            __builtin_nontemporal_store(r[j], out4 + base + j * NTHREADS);
        }
    }
}

extern "C" void kernel_launch(void* const* d_in, const int* in_sizes, int n_in,
                              void* d_out, int out_size, void* d_ws, size_t ws_size,
                              hipStream_t stream) {
    const float* x    = (const float*)d_in[0];
    const float* grid = (const float*)d_in[1];
    f32x4* out4       = (f32x4*)d_out;

    int total_chunks = in_sizes[0] * 2;    // 33,554,432 = 8 * 2048 * 256 * 8

    bspline_basis_kernel<<<NBLOCKS, NTHREADS, 0, stream>>>(x, grid, out4, total_chunks);
}

// Round 12
// 104.260 us; speedup vs baseline: 1.0343x; 1.0343x over previous
//
#include <hip/hip_runtime.h>

#define IN_FEATURES 512
#define NBLOCKS  2048
#define NTHREADS 256
#define JUNROLL  4        // 4 x 256 chunks = 16 KB contiguous per block per iter

typedef float f32x4 __attribute__((ext_vector_type(4)));

// Final structure (R10, confirmed optimum): dense moving 32 MB write window
// across all 2048 blocks AND 16 KB contiguous burst per block per iteration.
// Burst-length sweep: scattered=137us, 16KB=102.9us, 32KB=107.8us.
// Occupancy sweep: 8/16/32 waves/CU = 157/137/137 (at scattered layout).
__global__ __launch_bounds__(256) void bspline_basis_kernel(
    const float* __restrict__ x,
    const float* __restrict__ grid,
    f32x4* __restrict__ out4,
    int total_chunks)
{
    int t = threadIdx.x;
    int b = blockIdx.x;

    float g3    = grid[3];        // first in-range knot (= -0.5)
    float h     = grid[4] - g3;   // uniform spacing (= 0.4)
    float inv_h = 1.0f / h;

    int m0 = (t & 1) << 2;        // half of the 8-wide row (invariant)

    const int per_iter = NBLOCKS * NTHREADS * JUNROLL;   // 2,097,152 chunks

    for (int base = b * (NTHREADS * JUNROLL) + t; base < total_chunks; base += per_iter) {
        // ---- issue all 4 x-loads first (memory-level parallelism) ----
        float xv[JUNROLL];
        #pragma unroll
        for (int j = 0; j < JUNROLL; ++j) {
            int c = base + j * NTHREADS;
            xv[j] = x[c >> 1];
        }

        // ---- compute 4 chunks ----
        f32x4 r[JUNROLL];
        #pragma unroll
        for (int j = 0; j < JUNROLL; ++j) {
            float u  = (xv[j] - g3) * inv_h;
            float fj = floorf(u);
            int jo = (int)fj;
            jo = jo < 0 ? 0 : (jo > 4 ? 4 : jo);
            float tt = u - (float)jo;

            float omt  = 1.0f - tt;
            float t2   = tt * tt;
            float t3   = t2 * tt;
            float omt3 = omt * omt * omt;
            const float k6 = 1.0f / 6.0f;
            float b0 = omt3 * k6;
            float b1 = (3.0f * t3 - 6.0f * t2 + 4.0f) * k6;
            float b2 = (-3.0f * t3 + 3.0f * t2 + 3.0f * tt + 1.0f) * k6;
            float b3 = t3 * k6;

            f32x4 rr;
            #pragma unroll
            for (int q = 0; q < 4; ++q) {
                int s = (m0 + q) - jo;
                float val = 0.0f;
                val = (s == 0) ? b0 : val;
                val = (s == 1) ? b1 : val;
                val = (s == 2) ? b2 : val;
                val = (s == 3) ? b3 : val;
                rr[q] = val;
            }
            r[j] = rr;
        }

        // ---- 4 back-to-back stores: block covers 16 KB contiguous ----
        #pragma unroll
        for (int j = 0; j < JUNROLL; ++j) {
            __builtin_nontemporal_store(r[j], out4 + base + j * NTHREADS);
        }
    }
}

extern "C" void kernel_launch(void* const* d_in, const int* in_sizes, int n_in,
                              void* d_out, int out_size, void* d_ws, size_t ws_size,
                              hipStream_t stream) {
    const float* x    = (const float*)d_in[0];
    const float* grid = (const float*)d_in[1];
    f32x4* out4       = (f32x4*)d_out;

    int total_chunks = in_sizes[0] * 2;    // 33,554,432 = 16 * 2048 * 256 * 4

    bspline_basis_kernel<<<NBLOCKS, NTHREADS, 0, stream>>>(x, grid, out4, total_chunks);
}